// Round 13
// baseline (129.124 us; speedup 1.0000x reference)
//
#include <hip/hip_runtime.h>

// PopulationCoding, round 13: FUSED single kernel.
//  r12 decode: nsplit=8 ws round-trip = 134MB (~21us HBM) canceled the 8x8
//  fragment's LDS gain; epi LUT conflicts ~14us + gather ~10us.
//  Structure: 512 blocks (2/CU) x 4 waves, TM=TN=64.
//   P1 GEMM: each wave owns a K-quarter (128), 8x8 fragment (LDS 1.0 B/FMA,
//      chip floor 20.5us), wave-PRIVATE LDS staging -> zero barriers;
//      ordering via DS in-order + s_waitcnt lgkmcnt(0) + memory clobbers.
//      Register prefetch safe: launch_bounds(256,2) caps VGPR at 256 (~170
//      needed) -> the r2/r6/r8 spill mode cannot trigger.
//   P2 (1 barrier): cross-wave acc reduction via LDS (16B/lane layout,
//      conflict-free) + conv byte-LUT + rate-LUT build.
//   P3 (1 barrier): per-thread epi, 2 neurons (n = tid, tid+256 keeps reads
//      lane-consecutive). No ws traffic at all; d_ws unused.
// B=1024, IN=512, D=256, P=8, T=32. Output [1024,256] fp32.

constexpr int IN_DIM  = 512;
constexpr int D_DIM   = 256;
constexpr int NTOT    = 2048;   // D*P
constexpr int T_STEPS = 32;

constexpr int TM  = 64;
constexpr int TN  = 64;
constexpr int TKW = 128;   // K-range per wave (4 waves cover K=512)
constexpr int TK  = 32;    // staging chunk

// LDS map (bytes):
//  P1: wave w: Aw = smem + w*16896   [32][68] floats (8704 B)
//              Bw = Aw + 8704        [32][64] floats (8192 B)   total 67584
//  P2/P3: red float4-indexed ((wsrc*8+ri)*2+half)*64+lane  -> 65536 B
//         lut  at 65536  [3][256][4] floats (12288 B)
//         rlut at 77824  [256] floats (1024 B)
// max concurrent = 78848 B -> 2 blocks/CU (157696 <= 163840).

__global__ __launch_bounds__(256, 2)
void popcode_fused(const float* __restrict__ x,
                   const float* __restrict__ Wp,
                   const float* __restrict__ bp,
                   const float* __restrict__ thrs,
                   const float* __restrict__ rateW,
                   const float* __restrict__ rateB,
                   const float* __restrict__ c1w,
                   const float* __restrict__ c1b,
                   const float* __restrict__ c2w,
                   const float* __restrict__ c2b,
                   const float* __restrict__ fus,
                   float* __restrict__ out)
{
    __shared__ __align__(16) char smem[78848];

    const int tid  = threadIdx.x;
    const int w    = tid >> 6;     // wave 0..3
    const int lane = tid & 63;
    const int b0   = blockIdx.x * TM;
    const int c0   = blockIdx.y * TN;

    // ---------------- P1: GEMM, wave-private staging, no barriers --------
    float* Aw = reinterpret_cast<float*>(smem) + w * 4224;   // [32][68]
    float* Bw = Aw + 2176;                                   // [32][64]

    const int rg = lane >> 3;   // 0..7
    const int dl = lane & 7;    // 0..7
    const int r8 = rg * 8;
    const int c8 = dl * 8;
    const int kw = w * TKW;

    float acc[8][8];
#pragma unroll
    for (int i = 0; i < 8; ++i)
#pragma unroll
        for (int j = 0; j < 8; ++j) acc[i][j] = 0.f;

    float4 ra[8], rbv[8];

    auto load_regs = [&](int kc) {
#pragma unroll
        for (int i = 0; i < 8; ++i) {
            const int f = lane + 64 * i;               // 0..511
            ra[i] = *reinterpret_cast<const float4*>(
                x + (b0 + (f >> 3)) * IN_DIM + kc + (f & 7) * 4);
            rbv[i] = *reinterpret_cast<const float4*>(
                Wp + (size_t)(kc + (f >> 4)) * NTOT + c0 + (f & 15) * 4);
        }
    };
    auto write_lds = [&]() {
#pragma unroll
        for (int i = 0; i < 8; ++i) {
            const int f   = lane + 64 * i;
            const int row = f >> 3;                    // 0..63
            const int c4  = (f & 7) * 4;               // 0..28
            Aw[(c4 + 0) * 68 + row] = ra[i].x;
            Aw[(c4 + 1) * 68 + row] = ra[i].y;
            Aw[(c4 + 2) * 68 + row] = ra[i].z;
            Aw[(c4 + 3) * 68 + row] = ra[i].w;
            *reinterpret_cast<float4*>(Bw + (f >> 4) * 64 + (f & 15) * 4) = rbv[i];
        }
    };

    load_regs(kw);
#pragma unroll 1
    for (int ch = 0; ch < TKW / TK; ++ch) {
        // prior chunk's ds_reads issued before these writes (clobber keeps
        // program order; DS ops from one wave complete in order).
        __asm__ volatile("" ::: "memory");
        write_lds();
        if (ch + 1 < TKW / TK) load_regs(kw + (ch + 1) * TK);  // latency hidden
        __asm__ volatile("s_waitcnt lgkmcnt(0)" ::: "memory"); // writes visible

#pragma unroll 8
        for (int k = 0; k < TK; ++k) {
            const float4 a0 = *reinterpret_cast<const float4*>(Aw + k * 68 + r8);
            const float4 a1 = *reinterpret_cast<const float4*>(Aw + k * 68 + r8 + 4);
            const float4 u0 = *reinterpret_cast<const float4*>(Bw + k * 64 + c8);
            const float4 u1 = *reinterpret_cast<const float4*>(Bw + k * 64 + c8 + 4);
            const float ar[8] = {a0.x, a0.y, a0.z, a0.w, a1.x, a1.y, a1.z, a1.w};
            const float bc[8] = {u0.x, u0.y, u0.z, u0.w, u1.x, u1.y, u1.z, u1.w};
#pragma unroll
            for (int r = 0; r < 8; ++r)
#pragma unroll
                for (int c = 0; c < 8; ++c)
                    acc[r][c] += ar[r] * bc[c];
        }
    }

    // ---------------- P2: cross-wave reduction + LUT build ---------------
    __syncthreads();   // all waves done with their staging regions

    float* red  = reinterpret_cast<float*>(smem);            // 64 KB
    float* lut  = reinterpret_cast<float*>(smem + 65536);    // [3][256][4]
    float* rlut = reinterpret_cast<float*>(smem + 77824);    // [256]

#pragma unroll
    for (int ri = 0; ri < 8; ++ri) {
        *reinterpret_cast<float4*>(red + (((w * 8 + ri) * 2 + 0) * 64 + lane) * 4) =
            {acc[ri][0], acc[ri][1], acc[ri][2], acc[ri][3]};
        *reinterpret_cast<float4*>(red + (((w * 8 + ri) * 2 + 1) * 64 + lane) * 4) =
            {acc[ri][4], acc[ri][5], acc[ri][6], acc[ri][7]};
    }
    {
        float rv = 0.f;
#pragma unroll
        for (int p = 0; p < 8; ++p)
            rv += (float)((tid >> p) & 1) * rateW[p];
        rlut[tid] = rv;
    }
#pragma unroll
    for (int i = 0; i < 12; ++i) {
        const int e    = 256 * i + tid;      // 0..3071
        const int k    = e >> 10;
        const int byte = (e >> 2) & 255;
        const int c    = e & 3;
        float v = (k == 1) ? c1b[c] : 0.f;   // fold conv1 bias into tap 1
#pragma unroll
        for (int p = 0; p < 8; ++p)
            v = fmaf((float)((byte >> p) & 1), c1w[(c * 8 + p) * 3 + k], v);
        lut[e] = v;
    }
    __syncthreads();

    // ---------------- P3: per-thread epilogue, 2 neurons -----------------
    float thr8[8];
#pragma unroll
    for (int p = 0; p < 8; ++p) thr8[p] = thrs[p];
    float w2c[4];
#pragma unroll
    for (int c = 0; c < 4; ++c) w2c[c] = c2w[c];
    const float rb_ = rateB[0];
    const float bb2 = c2b[0];
    const float f0 = fus[0], f1 = fus[1];
    const float fm = fmaxf(f0, f1);
    const float e0 = __expf(f0 - fm), e1 = __expf(f1 - fm);
    const float inv = 1.f / (e0 + e1);
    const float fw0 = e0 * inv, fw1 = e1 * inv;

#pragma unroll 1
    for (int j = 0; j < 2; ++j) {
        const int ri = w + 4 * j;            // n = tid + 256*j -> ri, ln=lane
        // gather I across the 4 wave-partials (conflict-free: 16B/lane)
        float4 slo = {0.f, 0.f, 0.f, 0.f}, shi = {0.f, 0.f, 0.f, 0.f};
#pragma unroll
        for (int ws2 = 0; ws2 < 4; ++ws2) {
            const float4 a = *reinterpret_cast<const float4*>(
                red + (((ws2 * 8 + ri) * 2 + 0) * 64 + lane) * 4);
            const float4 b = *reinterpret_cast<const float4*>(
                red + (((ws2 * 8 + ri) * 2 + 1) * 64 + lane) * 4);
            slo.x += a.x; slo.y += a.y; slo.z += a.z; slo.w += a.w;
            shi.x += b.x; shi.y += b.y; shi.z += b.z; shi.w += b.w;
        }
        const float4 bq0 = *reinterpret_cast<const float4*>(bp + c0 + dl * 8);
        const float4 bq1 = *reinterpret_cast<const float4*>(bp + c0 + dl * 8 + 4);
        float Iv[8] = {slo.x + bq0.x, slo.y + bq0.y, slo.z + bq0.z, slo.w + bq0.w,
                       shi.x + bq1.x, shi.y + bq1.y, shi.z + bq1.z, shi.w + bq1.w};
        float Imt[8], mem[8];
        bool  spk[8];
#pragma unroll
        for (int p = 0; p < 8; ++p) {
            Imt[p] = Iv[p] - thr8[p];
            mem[p] = 0.f;
            spk[p] = false;
        }

        // LIF (exact fp32), spike byte per t packed 4-per-u32
        unsigned tb[8] = {0u, 0u, 0u, 0u, 0u, 0u, 0u, 0u};
#pragma unroll
        for (int t = 0; t < T_STEPS; ++t) {
            unsigned by = 0u;
#pragma unroll
            for (int p = 0; p < 8; ++p) {
                mem[p] = 0.95f * mem[p] + (spk[p] ? Imt[p] : Iv[p]);
                spk[p] = mem[p] > thr8[p];
                by |= spk[p] ? (1u << p) : 0u;
            }
            tb[t >> 2] |= by << (8 * (t & 3));
        }

        // conv + rate via byte LUTs
        float tacc = 0.f, rsum = 0.f;
        unsigned bprev = 0u;
        unsigned bcur  = tb[0] & 255u;
#pragma unroll
        for (int t = 0; t < T_STEPS; ++t) {
            const unsigned bnext =
                (t < 31) ? ((tb[(t + 1) >> 2] >> (8 * ((t + 1) & 3))) & 255u) : 0u;
            const float4 fa = *reinterpret_cast<const float4*>(lut + bprev * 4);
            const float4 fb = *reinterpret_cast<const float4*>(lut + 1024 + bcur * 4);
            const float4 fc = *reinterpret_cast<const float4*>(lut + 2048 + bnext * 4);
            rsum += rlut[bcur];
            const float h0_ = (fa.x + fb.x) + fc.x;
            const float h1_ = (fa.y + fb.y) + fc.y;
            const float h2_ = (fa.z + fb.z) + fc.z;
            const float h3_ = (fa.w + fb.w) + fc.w;
            tacc = fmaf(fmaxf(h0_, 0.f), w2c[0], tacc);
            tacc = fmaf(fmaxf(h1_, 0.f), w2c[1], tacc);
            tacc = fmaf(fmaxf(h2_, 0.f), w2c[2], tacc);
            tacc = fmaf(fmaxf(h3_, 0.f), w2c[3], tacc);
            bprev = bcur;
            bcur  = bnext;
        }
        const float rdec = rsum * (1.f / 32.f) + rb_;
        const float temp = tacc * (1.f / 32.f) + bb2;

        const int row = b0 + (lane >> 3) * 8 + ri;
        out[row * D_DIM + (c0 >> 3) + dl] = fw0 * rdec + fw1 * temp;
    }
}

extern "C" void kernel_launch(void* const* d_in, const int* in_sizes, int n_in,
                              void* d_out, int out_size, void* d_ws, size_t ws_size,
                              hipStream_t stream) {
    const float* x     = (const float*)d_in[0];
    const float* Wp    = (const float*)d_in[1];
    const float* bp    = (const float*)d_in[2];
    const float* thrs  = (const float*)d_in[3];
    const float* rateW = (const float*)d_in[4];
    const float* rateB = (const float*)d_in[5];
    const float* c1w   = (const float*)d_in[6];
    const float* c1b   = (const float*)d_in[7];
    const float* c2w   = (const float*)d_in[8];
    const float* c2b   = (const float*)d_in[9];
    const float* fus   = (const float*)d_in[10];
    float* out = (float*)d_out;

    dim3 grid(1024 / TM, NTOT / TN);   // 16 x 32 = 512 blocks = 2/CU
    popcode_fused<<<grid, dim3(256), 0, stream>>>(
        x, Wp, bp, thrs, rateW, rateB, c1w, c1b, c2w, c2b, fus, out);
}

// Round 14
// 128.545 us; speedup vs baseline: 1.0045x; 1.0045x over previous
//
#include <hip/hip_runtime.h>

// PopulationCoding, round 14 = r13 fused kernel, registers UNCAPPED.
//  r13 decode: launch_bounds(256,2) caps VGPR ~128 (observed (,4)->64);
//  kernel needs ~170 -> 92+spill, WRITE_SIZE 55MB of scratch. LDS (78.8KB)
//  already pins occupancy at 2 blocks/CU, so a VGPR cap buys nothing.
//  Single change: __launch_bounds__(256) plain (r8 evidence: uncapped
//  allocator goes to ~236 without spill).
// B=1024, IN=512, D=256, P=8, T=32. Output [1024,256] fp32.

constexpr int IN_DIM  = 512;
constexpr int D_DIM   = 256;
constexpr int NTOT    = 2048;   // D*P
constexpr int T_STEPS = 32;

constexpr int TM  = 64;
constexpr int TN  = 64;
constexpr int TKW = 128;   // K-range per wave (4 waves cover K=512)
constexpr int TK  = 32;    // staging chunk

// LDS map (bytes):
//  P1: wave w: Aw = smem + w*16896   [32][68] floats (8704 B)
//              Bw = Aw + 8704        [32][64] floats (8192 B)   total 67584
//  P2/P3: red float4-indexed ((wsrc*8+ri)*2+half)*64+lane  -> 65536 B
//         lut  at 65536  [3][256][4] floats (12288 B)
//         rlut at 77824  [256] floats (1024 B)
// max concurrent = 78848 B -> 2 blocks/CU (157696 <= 163840).

__global__ __launch_bounds__(256)
void popcode_fused(const float* __restrict__ x,
                   const float* __restrict__ Wp,
                   const float* __restrict__ bp,
                   const float* __restrict__ thrs,
                   const float* __restrict__ rateW,
                   const float* __restrict__ rateB,
                   const float* __restrict__ c1w,
                   const float* __restrict__ c1b,
                   const float* __restrict__ c2w,
                   const float* __restrict__ c2b,
                   const float* __restrict__ fus,
                   float* __restrict__ out)
{
    __shared__ __align__(16) char smem[78848];

    const int tid  = threadIdx.x;
    const int w    = tid >> 6;     // wave 0..3
    const int lane = tid & 63;
    const int b0   = blockIdx.x * TM;
    const int c0   = blockIdx.y * TN;

    // ---------------- P1: GEMM, wave-private staging, no barriers --------
    float* Aw = reinterpret_cast<float*>(smem) + w * 4224;   // [32][68]
    float* Bw = Aw + 2176;                                   // [32][64]

    const int rg = lane >> 3;   // 0..7
    const int dl = lane & 7;    // 0..7
    const int r8 = rg * 8;
    const int c8 = dl * 8;
    const int kw = w * TKW;

    float acc[8][8];
#pragma unroll
    for (int i = 0; i < 8; ++i)
#pragma unroll
        for (int j = 0; j < 8; ++j) acc[i][j] = 0.f;

    float4 ra[8], rbv[8];

    auto load_regs = [&](int kc) {
#pragma unroll
        for (int i = 0; i < 8; ++i) {
            const int f = lane + 64 * i;               // 0..511
            ra[i] = *reinterpret_cast<const float4*>(
                x + (b0 + (f >> 3)) * IN_DIM + kc + (f & 7) * 4);
            rbv[i] = *reinterpret_cast<const float4*>(
                Wp + (size_t)(kc + (f >> 4)) * NTOT + c0 + (f & 15) * 4);
        }
    };
    auto write_lds = [&]() {
#pragma unroll
        for (int i = 0; i < 8; ++i) {
            const int f   = lane + 64 * i;
            const int row = f >> 3;                    // 0..63
            const int c4  = (f & 7) * 4;               // 0..28
            Aw[(c4 + 0) * 68 + row] = ra[i].x;
            Aw[(c4 + 1) * 68 + row] = ra[i].y;
            Aw[(c4 + 2) * 68 + row] = ra[i].z;
            Aw[(c4 + 3) * 68 + row] = ra[i].w;
            *reinterpret_cast<float4*>(Bw + (f >> 4) * 64 + (f & 15) * 4) = rbv[i];
        }
    };

    load_regs(kw);
#pragma unroll 1
    for (int ch = 0; ch < TKW / TK; ++ch) {
        // prior chunk's ds_reads issued before these writes (clobber keeps
        // program order; DS ops from one wave complete in order).
        __asm__ volatile("" ::: "memory");
        write_lds();
        if (ch + 1 < TKW / TK) load_regs(kw + (ch + 1) * TK);  // latency hidden
        __asm__ volatile("s_waitcnt lgkmcnt(0)" ::: "memory"); // writes visible

#pragma unroll 8
        for (int k = 0; k < TK; ++k) {
            const float4 a0 = *reinterpret_cast<const float4*>(Aw + k * 68 + r8);
            const float4 a1 = *reinterpret_cast<const float4*>(Aw + k * 68 + r8 + 4);
            const float4 u0 = *reinterpret_cast<const float4*>(Bw + k * 64 + c8);
            const float4 u1 = *reinterpret_cast<const float4*>(Bw + k * 64 + c8 + 4);
            const float ar[8] = {a0.x, a0.y, a0.z, a0.w, a1.x, a1.y, a1.z, a1.w};
            const float bc[8] = {u0.x, u0.y, u0.z, u0.w, u1.x, u1.y, u1.z, u1.w};
#pragma unroll
            for (int r = 0; r < 8; ++r)
#pragma unroll
                for (int c = 0; c < 8; ++c)
                    acc[r][c] += ar[r] * bc[c];
        }
    }

    // ---------------- P2: cross-wave reduction + LUT build ---------------
    __syncthreads();   // all waves done with their staging regions

    float* red  = reinterpret_cast<float*>(smem);            // 64 KB
    float* lut  = reinterpret_cast<float*>(smem + 65536);    // [3][256][4]
    float* rlut = reinterpret_cast<float*>(smem + 77824);    // [256]

#pragma unroll
    for (int ri = 0; ri < 8; ++ri) {
        *reinterpret_cast<float4*>(red + (((w * 8 + ri) * 2 + 0) * 64 + lane) * 4) =
            {acc[ri][0], acc[ri][1], acc[ri][2], acc[ri][3]};
        *reinterpret_cast<float4*>(red + (((w * 8 + ri) * 2 + 1) * 64 + lane) * 4) =
            {acc[ri][4], acc[ri][5], acc[ri][6], acc[ri][7]};
    }
    {
        float rv = 0.f;
#pragma unroll
        for (int p = 0; p < 8; ++p)
            rv += (float)((tid >> p) & 1) * rateW[p];
        rlut[tid] = rv;
    }
#pragma unroll
    for (int i = 0; i < 12; ++i) {
        const int e    = 256 * i + tid;      // 0..3071
        const int k    = e >> 10;
        const int byte = (e >> 2) & 255;
        const int c    = e & 3;
        float v = (k == 1) ? c1b[c] : 0.f;   // fold conv1 bias into tap 1
#pragma unroll
        for (int p = 0; p < 8; ++p)
            v = fmaf((float)((byte >> p) & 1), c1w[(c * 8 + p) * 3 + k], v);
        lut[e] = v;
    }
    __syncthreads();

    // ---------------- P3: per-thread epilogue, 2 neurons -----------------
    float thr8[8];
#pragma unroll
    for (int p = 0; p < 8; ++p) thr8[p] = thrs[p];
    float w2c[4];
#pragma unroll
    for (int c = 0; c < 4; ++c) w2c[c] = c2w[c];
    const float rb_ = rateB[0];
    const float bb2 = c2b[0];
    const float f0 = fus[0], f1 = fus[1];
    const float fm = fmaxf(f0, f1);
    const float e0 = __expf(f0 - fm), e1 = __expf(f1 - fm);
    const float inv = 1.f / (e0 + e1);
    const float fw0 = e0 * inv, fw1 = e1 * inv;

#pragma unroll 1
    for (int j = 0; j < 2; ++j) {
        const int ri = w + 4 * j;            // n = tid + 256*j -> ri, ln=lane
        // gather I across the 4 wave-partials (conflict-free: 16B/lane)
        float4 slo = {0.f, 0.f, 0.f, 0.f}, shi = {0.f, 0.f, 0.f, 0.f};
#pragma unroll
        for (int ws2 = 0; ws2 < 4; ++ws2) {
            const float4 a = *reinterpret_cast<const float4*>(
                red + (((ws2 * 8 + ri) * 2 + 0) * 64 + lane) * 4);
            const float4 b = *reinterpret_cast<const float4*>(
                red + (((ws2 * 8 + ri) * 2 + 1) * 64 + lane) * 4);
            slo.x += a.x; slo.y += a.y; slo.z += a.z; slo.w += a.w;
            shi.x += b.x; shi.y += b.y; shi.z += b.z; shi.w += b.w;
        }
        const float4 bq0 = *reinterpret_cast<const float4*>(bp + c0 + dl * 8);
        const float4 bq1 = *reinterpret_cast<const float4*>(bp + c0 + dl * 8 + 4);
        float Iv[8] = {slo.x + bq0.x, slo.y + bq0.y, slo.z + bq0.z, slo.w + bq0.w,
                       shi.x + bq1.x, shi.y + bq1.y, shi.z + bq1.z, shi.w + bq1.w};
        float Imt[8], mem[8];
        bool  spk[8];
#pragma unroll
        for (int p = 0; p < 8; ++p) {
            Imt[p] = Iv[p] - thr8[p];
            mem[p] = 0.f;
            spk[p] = false;
        }

        // LIF (exact fp32), spike byte per t packed 4-per-u32
        unsigned tb[8] = {0u, 0u, 0u, 0u, 0u, 0u, 0u, 0u};
#pragma unroll
        for (int t = 0; t < T_STEPS; ++t) {
            unsigned by = 0u;
#pragma unroll
            for (int p = 0; p < 8; ++p) {
                mem[p] = 0.95f * mem[p] + (spk[p] ? Imt[p] : Iv[p]);
                spk[p] = mem[p] > thr8[p];
                by |= spk[p] ? (1u << p) : 0u;
            }
            tb[t >> 2] |= by << (8 * (t & 3));
        }

        // conv + rate via byte LUTs
        float tacc = 0.f, rsum = 0.f;
        unsigned bprev = 0u;
        unsigned bcur  = tb[0] & 255u;
#pragma unroll
        for (int t = 0; t < T_STEPS; ++t) {
            const unsigned bnext =
                (t < 31) ? ((tb[(t + 1) >> 2] >> (8 * ((t + 1) & 3))) & 255u) : 0u;
            const float4 fa = *reinterpret_cast<const float4*>(lut + bprev * 4);
            const float4 fb = *reinterpret_cast<const float4*>(lut + 1024 + bcur * 4);
            const float4 fc = *reinterpret_cast<const float4*>(lut + 2048 + bnext * 4);
            rsum += rlut[bcur];
            const float h0_ = (fa.x + fb.x) + fc.x;
            const float h1_ = (fa.y + fb.y) + fc.y;
            const float h2_ = (fa.z + fb.z) + fc.z;
            const float h3_ = (fa.w + fb.w) + fc.w;
            tacc = fmaf(fmaxf(h0_, 0.f), w2c[0], tacc);
            tacc = fmaf(fmaxf(h1_, 0.f), w2c[1], tacc);
            tacc = fmaf(fmaxf(h2_, 0.f), w2c[2], tacc);
            tacc = fmaf(fmaxf(h3_, 0.f), w2c[3], tacc);
            bprev = bcur;
            bcur  = bnext;
        }
        const float rdec = rsum * (1.f / 32.f) + rb_;
        const float temp = tacc * (1.f / 32.f) + bb2;

        const int row = b0 + (lane >> 3) * 8 + ri;
        out[row * D_DIM + (c0 >> 3) + dl] = fw0 * rdec + fw1 * temp;
    }
}

extern "C" void kernel_launch(void* const* d_in, const int* in_sizes, int n_in,
                              void* d_out, int out_size, void* d_ws, size_t ws_size,
                              hipStream_t stream) {
    const float* x     = (const float*)d_in[0];
    const float* Wp    = (const float*)d_in[1];
    const float* bp    = (const float*)d_in[2];
    const float* thrs  = (const float*)d_in[3];
    const float* rateW = (const float*)d_in[4];
    const float* rateB = (const float*)d_in[5];
    const float* c1w   = (const float*)d_in[6];
    const float* c1b   = (const float*)d_in[7];
    const float* c2w   = (const float*)d_in[8];
    const float* c2b   = (const float*)d_in[9];
    const float* fus   = (const float*)d_in[10];
    float* out = (float*)d_out;

    dim3 grid(1024 / TM, NTOT / TN);   // 16 x 32 = 512 blocks = 2/CU
    popcode_fused<<<grid, dim3(256), 0, stream>>>(
        x, Wp, bp, thrs, rateW, rateB, c1w, c1b, c2w, c2b, fus, out);
}

// Round 15
// 127.593 us; speedup vs baseline: 1.0120x; 1.0075x over previous
//
#include <hip/hip_runtime.h>

// PopulationCoding, round 15 = r14 fused kernel, spill mechanism excised.
//  r13/r14 decode: VGPR=92 + 55MB scratch IDENTICAL with and without
//  launch_bounds -> bounds never mattered. Cause: staging arrays captured
//  by-reference in lambdas + inline asm with "memory" clobber in the hot
//  loop -> allocas forced to stay materialized on stack (-> ~404B/thread
//  scratch traffic). Fix: no lambdas, no memory clobber. Ordering via
//  __builtin_amdgcn_s_waitcnt(0xc07f) (lgkm-only; vmcnt stays in flight)
//  + __builtin_amdgcn_wave_barrier() (compiler-level; per-wave DS ops are
//  HW-in-order).
// B=1024, IN=512, D=256, P=8, T=32. Output [1024,256] fp32.

constexpr int IN_DIM  = 512;
constexpr int D_DIM   = 256;
constexpr int NTOT    = 2048;   // D*P
constexpr int T_STEPS = 32;

constexpr int TM  = 64;
constexpr int TN  = 64;
constexpr int TKW = 128;   // K-range per wave (4 waves cover K=512)
constexpr int TK  = 32;    // staging chunk
constexpr int NCH = TKW / TK;   // 4

// LDS map (bytes):
//  P1: wave w: Aw = smem + w*16896   [32][68] floats (8704 B)
//              Bw = Aw + 8704        [32][64] floats (8192 B)   total 67584
//  P2/P3: red float4-indexed ((wsrc*8+ri)*2+half)*64+lane  -> 65536 B
//         lut  at 65536  [3][256][4] floats (12288 B)
//         rlut at 77824  [256] floats (1024 B)
// max concurrent = 78848 B -> 2 blocks/CU.

__global__ __launch_bounds__(256)
void popcode_fused(const float* __restrict__ x,
                   const float* __restrict__ Wp,
                   const float* __restrict__ bp,
                   const float* __restrict__ thrs,
                   const float* __restrict__ rateW,
                   const float* __restrict__ rateB,
                   const float* __restrict__ c1w,
                   const float* __restrict__ c1b,
                   const float* __restrict__ c2w,
                   const float* __restrict__ c2b,
                   const float* __restrict__ fus,
                   float* __restrict__ out)
{
    __shared__ __align__(16) char smem[78848];

    const int tid  = threadIdx.x;
    const int w    = tid >> 6;     // wave 0..3
    const int lane = tid & 63;
    const int b0   = blockIdx.x * TM;
    const int c0   = blockIdx.y * TN;

    // ---------------- P1: GEMM, wave-private staging, no barriers --------
    float* Aw = reinterpret_cast<float*>(smem) + w * 4224;   // [32][68]
    float* Bw = Aw + 2176;                                   // [32][64]

    const int rg = lane >> 3;   // 0..7
    const int dl = lane & 7;    // 0..7
    const int r8 = rg * 8;
    const int c8 = dl * 8;
    const int kw = w * TKW;

    float acc[8][8];
#pragma unroll
    for (int i = 0; i < 8; ++i)
#pragma unroll
        for (int j = 0; j < 8; ++j) acc[i][j] = 0.f;

    float4 ra[8], rbv[8];

    // prologue: loads for chunk 0
#pragma unroll
    for (int i = 0; i < 8; ++i) {
        const int f = lane + 64 * i;               // 0..511
        ra[i] = *reinterpret_cast<const float4*>(
            x + (b0 + (f >> 3)) * IN_DIM + kw + (f & 7) * 4);
        rbv[i] = *reinterpret_cast<const float4*>(
            Wp + (size_t)(kw + (f >> 4)) * NTOT + c0 + (f & 15) * 4);
    }

#pragma unroll 1
    for (int ch = 0; ch < NCH; ++ch) {
        // stage current chunk into this wave's private LDS region
#pragma unroll
        for (int i = 0; i < 8; ++i) {
            const int f   = lane + 64 * i;
            const int row = f >> 3;                // 0..63
            const int c4  = (f & 7) * 4;           // 0..28
            Aw[(c4 + 0) * 68 + row] = ra[i].x;
            Aw[(c4 + 1) * 68 + row] = ra[i].y;
            Aw[(c4 + 2) * 68 + row] = ra[i].z;
            Aw[(c4 + 3) * 68 + row] = ra[i].w;
            *reinterpret_cast<float4*>(Bw + (f >> 4) * 64 + (f & 15) * 4) = rbv[i];
        }
        // prefetch next chunk (stays in flight across compute; lgkm wait
        // below does NOT drain vmcnt)
        if (ch + 1 < NCH) {
            const int kc = kw + (ch + 1) * TK;
#pragma unroll
            for (int i = 0; i < 8; ++i) {
                const int f = lane + 64 * i;
                ra[i] = *reinterpret_cast<const float4*>(
                    x + (b0 + (f >> 3)) * IN_DIM + kc + (f & 7) * 4);
                rbv[i] = *reinterpret_cast<const float4*>(
                    Wp + (size_t)(kc + (f >> 4)) * NTOT + c0 + (f & 15) * 4);
            }
        }
        __builtin_amdgcn_s_waitcnt(0xc07f);   // lgkmcnt(0): ds_writes done
        __builtin_amdgcn_wave_barrier();      // keep reads below writes

#pragma unroll 8
        for (int k = 0; k < TK; ++k) {
            const float4 a0 = *reinterpret_cast<const float4*>(Aw + k * 68 + r8);
            const float4 a1 = *reinterpret_cast<const float4*>(Aw + k * 68 + r8 + 4);
            const float4 u0 = *reinterpret_cast<const float4*>(Bw + k * 64 + c8);
            const float4 u1 = *reinterpret_cast<const float4*>(Bw + k * 64 + c8 + 4);
            const float ar[8] = {a0.x, a0.y, a0.z, a0.w, a1.x, a1.y, a1.z, a1.w};
            const float bc[8] = {u0.x, u0.y, u0.z, u0.w, u1.x, u1.y, u1.z, u1.w};
#pragma unroll
            for (int r = 0; r < 8; ++r)
#pragma unroll
                for (int c = 0; c < 8; ++c)
                    acc[r][c] += ar[r] * bc[c];
        }
        __builtin_amdgcn_wave_barrier();      // keep next writes below reads
    }

    // ---------------- P2: cross-wave reduction + LUT build ---------------
    __syncthreads();   // all waves done with their staging regions

    float* red  = reinterpret_cast<float*>(smem);            // 64 KB
    float* lut  = reinterpret_cast<float*>(smem + 65536);    // [3][256][4]
    float* rlut = reinterpret_cast<float*>(smem + 77824);    // [256]

#pragma unroll
    for (int ri = 0; ri < 8; ++ri) {
        *reinterpret_cast<float4*>(red + (((w * 8 + ri) * 2 + 0) * 64 + lane) * 4) =
            {acc[ri][0], acc[ri][1], acc[ri][2], acc[ri][3]};
        *reinterpret_cast<float4*>(red + (((w * 8 + ri) * 2 + 1) * 64 + lane) * 4) =
            {acc[ri][4], acc[ri][5], acc[ri][6], acc[ri][7]};
    }
    {
        float rv = 0.f;
#pragma unroll
        for (int p = 0; p < 8; ++p)
            rv += (float)((tid >> p) & 1) * rateW[p];
        rlut[tid] = rv;
    }
#pragma unroll
    for (int i = 0; i < 12; ++i) {
        const int e    = 256 * i + tid;      // 0..3071
        const int k    = e >> 10;
        const int byte = (e >> 2) & 255;
        const int c    = e & 3;
        float v = (k == 1) ? c1b[c] : 0.f;   // fold conv1 bias into tap 1
#pragma unroll
        for (int p = 0; p < 8; ++p)
            v = fmaf((float)((byte >> p) & 1), c1w[(c * 8 + p) * 3 + k], v);
        lut[e] = v;
    }
    __syncthreads();

    // ---------------- P3: per-thread epilogue, 2 neurons -----------------
    float thr8[8];
#pragma unroll
    for (int p = 0; p < 8; ++p) thr8[p] = thrs[p];
    float w2c[4];
#pragma unroll
    for (int c = 0; c < 4; ++c) w2c[c] = c2w[c];
    const float rb_ = rateB[0];
    const float bb2 = c2b[0];
    const float f0 = fus[0], f1 = fus[1];
    const float fm = fmaxf(f0, f1);
    const float e0 = __expf(f0 - fm), e1 = __expf(f1 - fm);
    const float inv = 1.f / (e0 + e1);
    const float fw0 = e0 * inv, fw1 = e1 * inv;

#pragma unroll 1
    for (int j = 0; j < 2; ++j) {
        const int ri = w + 4 * j;            // n = tid + 256*j -> ri, ln=lane
        // gather I across the 4 wave-partials (conflict-free: 16B/lane)
        float4 slo = {0.f, 0.f, 0.f, 0.f}, shi = {0.f, 0.f, 0.f, 0.f};
#pragma unroll
        for (int ws2 = 0; ws2 < 4; ++ws2) {
            const float4 a = *reinterpret_cast<const float4*>(
                red + (((ws2 * 8 + ri) * 2 + 0) * 64 + lane) * 4);
            const float4 b = *reinterpret_cast<const float4*>(
                red + (((ws2 * 8 + ri) * 2 + 1) * 64 + lane) * 4);
            slo.x += a.x; slo.y += a.y; slo.z += a.z; slo.w += a.w;
            shi.x += b.x; shi.y += b.y; shi.z += b.z; shi.w += b.w;
        }
        const float4 bq0 = *reinterpret_cast<const float4*>(bp + c0 + dl * 8);
        const float4 bq1 = *reinterpret_cast<const float4*>(bp + c0 + dl * 8 + 4);
        float Iv[8] = {slo.x + bq0.x, slo.y + bq0.y, slo.z + bq0.z, slo.w + bq0.w,
                       shi.x + bq1.x, shi.y + bq1.y, shi.z + bq1.z, shi.w + bq1.w};
        float Imt[8], mem[8];
        bool  spk[8];
#pragma unroll
        for (int p = 0; p < 8; ++p) {
            Imt[p] = Iv[p] - thr8[p];
            mem[p] = 0.f;
            spk[p] = false;
        }

        // LIF (exact fp32), spike byte per t packed 4-per-u32
        unsigned tb[8] = {0u, 0u, 0u, 0u, 0u, 0u, 0u, 0u};
#pragma unroll
        for (int t = 0; t < T_STEPS; ++t) {
            unsigned by = 0u;
#pragma unroll
            for (int p = 0; p < 8; ++p) {
                mem[p] = 0.95f * mem[p] + (spk[p] ? Imt[p] : Iv[p]);
                spk[p] = mem[p] > thr8[p];
                by |= spk[p] ? (1u << p) : 0u;
            }
            tb[t >> 2] |= by << (8 * (t & 3));
        }

        // conv + rate via byte LUTs
        float tacc = 0.f, rsum = 0.f;
        unsigned bprev = 0u;
        unsigned bcur  = tb[0] & 255u;
#pragma unroll
        for (int t = 0; t < T_STEPS; ++t) {
            const unsigned bnext =
                (t < 31) ? ((tb[(t + 1) >> 2] >> (8 * ((t + 1) & 3))) & 255u) : 0u;
            const float4 fa = *reinterpret_cast<const float4*>(lut + bprev * 4);
            const float4 fb = *reinterpret_cast<const float4*>(lut + 1024 + bcur * 4);
            const float4 fc = *reinterpret_cast<const float4*>(lut + 2048 + bnext * 4);
            rsum += rlut[bcur];
            const float h0_ = (fa.x + fb.x) + fc.x;
            const float h1_ = (fa.y + fb.y) + fc.y;
            const float h2_ = (fa.z + fb.z) + fc.z;
            const float h3_ = (fa.w + fb.w) + fc.w;
            tacc = fmaf(fmaxf(h0_, 0.f), w2c[0], tacc);
            tacc = fmaf(fmaxf(h1_, 0.f), w2c[1], tacc);
            tacc = fmaf(fmaxf(h2_, 0.f), w2c[2], tacc);
            tacc = fmaf(fmaxf(h3_, 0.f), w2c[3], tacc);
            bprev = bcur;
            bcur  = bnext;
        }
        const float rdec = rsum * (1.f / 32.f) + rb_;
        const float temp = tacc * (1.f / 32.f) + bb2;

        const int row = b0 + (lane >> 3) * 8 + ri;
        out[row * D_DIM + (c0 >> 3) + dl] = fw0 * rdec + fw1 * temp;
    }
}

extern "C" void kernel_launch(void* const* d_in, const int* in_sizes, int n_in,
                              void* d_out, int out_size, void* d_ws, size_t ws_size,
                              hipStream_t stream) {
    const float* x     = (const float*)d_in[0];
    const float* Wp    = (const float*)d_in[1];
    const float* bp    = (const float*)d_in[2];
    const float* thrs  = (const float*)d_in[3];
    const float* rateW = (const float*)d_in[4];
    const float* rateB = (const float*)d_in[5];
    const float* c1w   = (const float*)d_in[6];
    const float* c1b   = (const float*)d_in[7];
    const float* c2w   = (const float*)d_in[8];
    const float* c2b   = (const float*)d_in[9];
    const float* fus   = (const float*)d_in[10];
    float* out = (float*)d_out;

    dim3 grid(1024 / TM, NTOT / TN);   // 16 x 32 = 512 blocks = 2/CU
    popcode_fused<<<grid, dim3(256), 0, stream>>>(
        x, Wp, bp, thrs, rateW, rateB, c1w, c1b, c2w, c2b, fus, out);
}

// Round 16
// 127.133 us; speedup vs baseline: 1.0157x; 1.0036x over previous
//
#include <hip/hip_runtime.h>

// PopulationCoding, round 16: best-known split, both floors attacked.
//  Ledger (fixed overhead 63.5us): r11 = gemm 31 (at 1.5B/FMA LDS floor)
//  + epi 26 (near VALU floor). Fused path abandoned (3x identical
//  unexplained 55MB spill, and 64us > split's 57.5us anyway).
//  K1: 8rx8c fragment (1.0 B/FMA, floor 20.4us), TM=128/TN=64/TK=32,
//      nsplit=4 (ws cost unchanged vs r11), 128-thr blocks, 1024 blocks,
//      plain bounds, r11's staging idiom, no prefetch arrays.
//  K2: partner = lane^32 within the SAME wave: nibble exchange + final
//      reduce via __shfl_xor (removes 2 barriers + exch LDS); rate via
//      __popc (drops rlut); 1 barrier total. All reg-array indices static.
// B=1024, IN=512, D=256, P=8, T=32. Output [1024,256] fp32.

constexpr int IN_DIM  = 512;
constexpr int D_DIM   = 256;
constexpr int NTOT    = 2048;   // D*P
constexpr int T_STEPS = 32;

constexpr int TM = 128;
constexpr int TN = 64;
constexpr int TK = 32;
constexpr int NSPLIT = 4;
constexpr int KSPLIT = IN_DIM / NSPLIT;   // 128 -> 4 chunks of 32

// ---------------------------------------------------------------- K1: GEMM
__global__ __launch_bounds__(128)
void popcode_gemm(const float* __restrict__ x,
                  const float* __restrict__ Wp,
                  float* __restrict__ ws)    // [4][1024][2048] partial I
{
    // As [k][row] stride 132 (16B-aligned row-quads): 8-row fragment =
    // 2 b128, banks 4k+8rg -> 2-way aliased (free) + broadcast.
    // Bs [k][col] stride 64: b128 at 8dl / 8dl+4 -> 2-way (free).
    // LDS 16.9K + 8K = 24.9KB.
    __shared__ float As[TK][TM + 4];
    __shared__ float Bs[TK][TN];

    const int tid = threadIdx.x;   // 0..127
    const int b0  = blockIdx.x * TM;
    const int c0  = blockIdx.y * TN;
    const int k0  = blockIdx.z * KSPLIT;
    const int rg  = tid >> 3;      // 0..15
    const int dl  = tid & 7;       // 0..7
    const int r8  = rg * 8;        // first of this thread's 8 rows
    const int c8  = dl * 8;

    float acc[8][8];
#pragma unroll
    for (int i = 0; i < 8; ++i)
#pragma unroll
        for (int j = 0; j < 8; ++j) acc[i][j] = 0.f;

    for (int kc = k0; kc < k0 + KSPLIT; kc += TK) {
        // stage A: 128 rows x 32 k, 128 thr x 8 float4; transpose into As.
        // writes: bank (4*c4 + 4j + row) -> 2-way (free).
#pragma unroll
        for (int i = 0; i < 8; ++i) {
            const int f   = tid + 128 * i;       // 0..1023
            const int row = f >> 3;              // 0..127
            const int c4  = (f & 7) * 4;         // 0..28
            const float4 v =
                *reinterpret_cast<const float4*>(x + (b0 + row) * IN_DIM + kc + c4);
            As[c4 + 0][row] = v.x;
            As[c4 + 1][row] = v.y;
            As[c4 + 2][row] = v.z;
            As[c4 + 3][row] = v.w;
        }
        // stage B: 32 rows x 64 cols, 128 thr x 4 float4, row-major b128
#pragma unroll
        for (int i = 0; i < 4; ++i) {
            const int f  = tid + 128 * i;        // 0..511
            const int r  = f >> 4;               // 0..31
            const int c4 = (f & 15) * 4;
            *reinterpret_cast<float4*>(&Bs[r][c4]) =
                *reinterpret_cast<const float4*>(Wp + (kc + r) * NTOT + c0 + c4);
        }
        __syncthreads();

#pragma unroll 8
        for (int k = 0; k < TK; ++k) {
            const float4 a0 = *reinterpret_cast<const float4*>(&As[k][r8]);
            const float4 a1 = *reinterpret_cast<const float4*>(&As[k][r8 + 4]);
            const float4 u0 = *reinterpret_cast<const float4*>(&Bs[k][c8]);
            const float4 u1 = *reinterpret_cast<const float4*>(&Bs[k][c8 + 4]);
            const float ar[8] = {a0.x, a0.y, a0.z, a0.w, a1.x, a1.y, a1.z, a1.w};
            const float bc[8] = {u0.x, u0.y, u0.z, u0.w, u1.x, u1.y, u1.z, u1.w};
#pragma unroll
            for (int r = 0; r < 8; ++r)
#pragma unroll
                for (int c = 0; c < 8; ++c)
                    acc[r][c] += ar[r] * bc[c];
        }
        __syncthreads();
    }

    float* dst = ws + (size_t)blockIdx.z * 1024 * NTOT;
#pragma unroll
    for (int bi = 0; bi < 8; ++bi) {
        float* p = dst + (size_t)(b0 + r8 + bi) * NTOT + c0 + c8;
        *reinterpret_cast<float4*>(p)     = {acc[bi][0], acc[bi][1], acc[bi][2], acc[bi][3]};
        *reinterpret_cast<float4*>(p + 4) = {acc[bi][4], acc[bi][5], acc[bi][6], acc[bi][7]};
    }
}

// ------------------------------------------------------------ K2: epilogue
// Partner threads = (lane, lane^32) in the SAME wave share one neuron:
// h = lane>>5 selects p-half (LIF) and t-half (conv). Exchange via shfl.
__global__ __launch_bounds__(256)
void popcode_epi(const float* __restrict__ ws,
                 const float* __restrict__ bp,
                 const float* __restrict__ thrs,
                 const float* __restrict__ rateW,
                 const float* __restrict__ rateB,
                 const float* __restrict__ c1w,
                 const float* __restrict__ c1b,
                 const float* __restrict__ c2w,
                 const float* __restrict__ c2b,
                 const float* __restrict__ fus,
                 float* __restrict__ out)
{
    __shared__ float lut[3][256][4];     // 12 KB, conv1 bias folded in tap 1

    const int tid  = threadIdx.x;
    const int wv   = tid >> 6;            // 0..3
    const int lane = tid & 63;
    const int l5   = lane & 31;
    const int h    = lane >> 5;           // 0: p0-3/t0-15, 1: p4-7/t16-31
    const int n    = blockIdx.x * 128 + wv * 32 + l5;   // neuron id
    const int b    = n >> 8;
    const int d    = n & 255;

    // ---- build conv LUT (once per block), then single barrier ----
#pragma unroll
    for (int i = 0; i < 12; ++i) {
        const int e    = 256 * i + tid;      // 0..3071
        const int k    = e >> 10;
        const int byte = (e >> 2) & 255;
        const int c    = e & 3;
        float v = (k == 1) ? c1b[c] : 0.f;
#pragma unroll
        for (int p = 0; p < 8; ++p)
            v = fmaf((float)((byte >> p) & 1), c1w[(c * 8 + p) * 3 + k], v);
        lut[0][0][0 * 0] = lut[0][0][0];     // no-op to keep layout obvious
        (&lut[0][0][0])[e] = v;
    }
    __syncthreads();

    // ---- uniform scalars ----
    float w2c[4];
#pragma unroll
    for (int c = 0; c < 4; ++c) w2c[c] = c2w[c];
    const float rb_ = rateB[0];
    const float bb2 = c2b[0];
    const float f0 = fus[0], f1 = fus[1];
    const float fm = fmaxf(f0, f1);
    const float e0 = __expf(f0 - fm), e1 = __expf(f1 - fm);
    const float inv = 1.f / (e0 + e1);
    const float fw0 = e0 * inv, fw1 = e1 * inv;

    // ---- gather I for this thread's 4 p's: sum the 4 k-slices ----
    const size_t base  = (size_t)n * 8 + h * 4;
    const size_t slice = (size_t)1024 * NTOT;
    float4 iv = *reinterpret_cast<const float4*>(ws + base);
#pragma unroll
    for (int s = 1; s < NSPLIT; ++s) {
        const float4 q = *reinterpret_cast<const float4*>(ws + s * slice + base);
        iv.x += q.x; iv.y += q.y; iv.z += q.z; iv.w += q.w;
    }
    const float4 bpv = *reinterpret_cast<const float4*>(bp + d * 8 + h * 4);
    const float4 tv  = *reinterpret_cast<const float4*>(thrs + h * 4);
    const float4 rwv = *reinterpret_cast<const float4*>(rateW + h * 4);
    float Iv[4]  = {iv.x + bpv.x, iv.y + bpv.y, iv.z + bpv.z, iv.w + bpv.w};
    float thr[4] = {tv.x, tv.y, tv.z, tv.w};
    float Imt[4], mem[4];
    bool  spk[4];
#pragma unroll
    for (int p = 0; p < 4; ++p) {
        Imt[p] = Iv[p] - thr[p];
        mem[p] = 0.f;
        spk[p] = false;
    }

    // ---- LIF for 4 p's, nibble per t, 8 t per u32 ----
    unsigned nib[4] = {0u, 0u, 0u, 0u};
#pragma unroll
    for (int t = 0; t < T_STEPS; ++t) {
        unsigned nb = 0u;
#pragma unroll
        for (int p = 0; p < 4; ++p) {
            mem[p] = 0.95f * mem[p] + (spk[p] ? Imt[p] : Iv[p]);
            spk[p] = mem[p] > thr[p];
            nb |= spk[p] ? (1u << p) : 0u;
        }
        nib[t >> 3] |= nb << (4 * (t & 7));
    }

    // ---- rate branch via popc on own chains (partner added in reduce) ----
    float rsum = 0.f;
    {
        const float rw4[4] = {rwv.x, rwv.y, rwv.z, rwv.w};
#pragma unroll
        for (int j = 0; j < 4; ++j) {
            int cnt = 0;
#pragma unroll
            for (int wd = 0; wd < 4; ++wd)
                cnt += __popc((nib[wd] >> j) & 0x11111111u);
            rsum += (float)cnt * rw4[j];
        }
    }

    // ---- exchange nibbles with partner lane (same wave, lane^32) ----
    unsigned pr[4];
#pragma unroll
    for (int wd = 0; wd < 4; ++wd)
        pr[wd] = (unsigned)__shfl_xor((int)nib[wd], 32, 64);
    unsigned lo[4], hi[4];
#pragma unroll
    for (int wd = 0; wd < 4; ++wd) {
        lo[wd] = h ? pr[wd]  : nib[wd];   // p0..3 nibbles, all 32 t
        hi[wd] = h ? nib[wd] : pr[wd];    // p4..7 nibbles, all 32 t
    }
    // active words for this lane's t-half (static indices)
    const unsigned awL0 = h ? lo[2] : lo[0];
    const unsigned awL1 = h ? lo[3] : lo[1];
    const unsigned awH0 = h ? hi[2] : hi[0];
    const unsigned awH1 = h ? hi[3] : hi[1];
    // boundary bytes
    const unsigned b15 = ((lo[1] >> 28) & 15u) | (((hi[1] >> 28) & 15u) << 4);
    const unsigned b16 = (lo[2] & 15u) | ((hi[2] & 15u) << 4);

    // ---- conv over this lane's 16 t ----
    const float* lutf = &lut[0][0][0];
    float tacc = 0.f;
    unsigned bprev = h ? b15 : 0u;
    unsigned bcur  = (awL0 & 15u) | ((awH0 & 15u) << 4);
#pragma unroll
    for (int i = 0; i < 16; ++i) {
        unsigned bnext;
        if (i < 15) {
            const int wd = (i + 1) >> 3;          // 0 or 1, static
            const int s  = 4 * ((i + 1) & 7);     // static
            const unsigned wl = wd ? awL1 : awL0;
            const unsigned wh = wd ? awH1 : awH0;
            bnext = ((wl >> s) & 15u) | (((wh >> s) & 15u) << 4);
        } else {
            bnext = h ? 0u : b16;
        }
        const float4 fa = *reinterpret_cast<const float4*>(lutf + bprev * 4);
        const float4 fb = *reinterpret_cast<const float4*>(lutf + 1024 + bcur * 4);
        const float4 fc = *reinterpret_cast<const float4*>(lutf + 2048 + bnext * 4);
        const float h0_ = (fa.x + fb.x) + fc.x;
        const float h1_ = (fa.y + fb.y) + fc.y;
        const float h2_ = (fa.z + fb.z) + fc.z;
        const float h3_ = (fa.w + fb.w) + fc.w;
        tacc = fmaf(fmaxf(h0_, 0.f), w2c[0], tacc);
        tacc = fmaf(fmaxf(h1_, 0.f), w2c[1], tacc);
        tacc = fmaf(fmaxf(h2_, 0.f), w2c[2], tacc);
        tacc = fmaf(fmaxf(h3_, 0.f), w2c[3], tacc);
        bprev = bcur;
        bcur  = bnext;
    }

    // ---- combine with partner (shfl), write ----
    rsum += __shfl_xor(rsum, 32, 64);
    tacc += __shfl_xor(tacc, 32, 64);
    if (h == 0) {
        const float rdec = rsum * (1.f / 32.f) + rb_;
        const float temp = tacc * (1.f / 32.f) + bb2;
        out[b * D_DIM + d] = fw0 * rdec + fw1 * temp;
    }
}

extern "C" void kernel_launch(void* const* d_in, const int* in_sizes, int n_in,
                              void* d_out, int out_size, void* d_ws, size_t ws_size,
                              hipStream_t stream) {
    const float* x     = (const float*)d_in[0];
    const float* Wp    = (const float*)d_in[1];
    const float* bp    = (const float*)d_in[2];
    const float* thrs  = (const float*)d_in[3];
    const float* rateW = (const float*)d_in[4];
    const float* rateB = (const float*)d_in[5];
    const float* c1w   = (const float*)d_in[6];
    const float* c1b   = (const float*)d_in[7];
    const float* c2w   = (const float*)d_in[8];
    const float* c2b   = (const float*)d_in[9];
    const float* fus   = (const float*)d_in[10];
    float* out = (float*)d_out;
    float* ws  = (float*)d_ws;

    dim3 g1(1024 / TM, NTOT / TN, NSPLIT);   // 8 x 32 x 4 = 1024 blocks
    popcode_gemm<<<g1, dim3(128), 0, stream>>>(x, Wp, ws);

    popcode_epi<<<dim3(2048), dim3(256), 0, stream>>>(
        ws, bp, thrs, rateW, rateB, c1w, c1b, c2w, c2b, fus, out);
}